// Round 6
// baseline (606.697 us; speedup 1.0000x reference)
//
#include <hip/hip_runtime.h>
#include <hip/hip_fp16.h>

typedef _Float16 half8 __attribute__((ext_vector_type(8)));
typedef float f32x4 __attribute__((ext_vector_type(4)));

#define N_ROWS 4096
#define E_DIM 16384
#define R_DIM 512
#define D_DIM 256

#define BM 128
#define BK 64
#define SSPLIT 4
#define KC (E_DIM / SSPLIT)   // 4096 per K-chunk

// workspace byte offsets
#define WENT_OFF 0ull
#define WENT_BYTES ((size_t)D_DIM * E_DIM * 2)   // 8388608
#define WREL_OFF (WENT_OFF + WENT_BYTES)
#define WREL_BYTES ((size_t)D_DIM * R_DIM * 2)   // 262144
#define P_OFF (WREL_OFF + WREL_BYTES)            // partials: [4][8192][256] fp16 = 16 MB

__device__ __forceinline__ void glds16(const void* g, void* l) {
  __builtin_amdgcn_global_load_lds((const __attribute__((address_space(1))) void*)g,
                                   (__attribute__((address_space(3))) void*)l, 16, 0, 0);
}

__device__ __forceinline__ half8 cvt8(float4 a, float4 b) {
  half8 h;
  h[0] = (_Float16)a.x; h[1] = (_Float16)a.y; h[2] = (_Float16)a.z; h[3] = (_Float16)a.w;
  h[4] = (_Float16)b.x; h[5] = (_Float16)b.y; h[6] = (_Float16)b.z; h[7] = (_Float16)b.w;
  return h;
}

// f32 [D][K] weights -> fp16, laid out as K/64 tiles of [256 rows][8 16B-blocks],
// with block index XOR-swizzled by (d&7) so that linear global_load_lds staging
// yields conflict-free ds_read_b128 B-fragment reads.
__global__ void convert_w(const float* __restrict__ src, _Float16* __restrict__ dst, int K) {
  int p = blockIdx.x * blockDim.x + threadIdx.x;  // one 16B block (8 fp16) per thread
  int kt  = p >> 11;        // / (256 rows * 8 blocks)
  int rem = p & 2047;
  int d   = rem >> 3;
  int jp  = rem & 7;        // swizzled position
  int j   = jp ^ (d & 7);   // source block within row
  const float* s = src + (size_t)d * K + (size_t)kt * 64 + (size_t)j * 8;
  float4 a = *(const float4*)s;
  float4 b = *(const float4*)(s + 4);
  *(half8*)(dst + (size_t)p * 8) = cvt8(a, b);
}

// Tall-skinny GEMM: C[8192 x 256] = [x;y] @ W_ent^T, K-split into 4 chunks,
// fp16 partials written to P[kc][8192][256].
__global__ __launch_bounds__(512, 2) void main_gemm(
    const float* __restrict__ X, const float* __restrict__ Y,
    const _Float16* __restrict__ Wf, _Float16* __restrict__ P) {
  __shared__ __align__(16) _Float16 xs[BM * BK];      // 16 KB, XOR-swizzled rows
  __shared__ __align__(16) _Float16 wsh[D_DIM * BK];  // 32 KB, pre-swizzled in ws

  const int bid = blockIdx.x;
  const int x7  = bid & 7;                       // ~XCD id under round-robin dispatch
  const int kcid = x7 >> 1;                      // K-chunk: 2 XCDs share one chunk (L2-resident W)
  const int mt   = ((bid >> 3) << 1) | (x7 & 1); // 0..63 M-tile over stacked 8192 rows
  const int t = threadIdx.x;
  const int w = t >> 6, l = t & 63;
  const int lr = l & 15, lg = l >> 4;
  const int wr = w >> 2, wc = w & 3;             // wave grid 2x4, wave tile 64x64

  const float* Abase; int row0;
  if (mt < 32) { Abase = X; row0 = mt * BM; } else { Abase = Y; row0 = (mt - 32) * BM; }

  // x staging: thread -> (row sm, 16-float segment sseg)
  const int sm = t >> 2, sseg = t & 3;
  const float* srow = Abase + (size_t)(row0 + sm) * E_DIM + (size_t)kcid * KC + (size_t)sseg * 16;
  _Float16* xw0 = xs + sm * BK + (((2 * sseg    ) ^ (sm & 7)) * 8);
  _Float16* xw1 = xs + sm * BK + (((2 * sseg + 1) ^ (sm & 7)) * 8);

  const char* wtile0 = (const char*)Wf + (size_t)kcid * (KC / BK) * ((size_t)D_DIM * BK * 2)
                       + (size_t)w * 4096 + (size_t)l * 16;
  char* wldst = (char*)wsh + w * 4096;

  f32x4 acc[4][4] = {};

  for (int ktl = 0; ktl < KC / BK; ++ktl) {   // 64 iterations
    // stage W tile via async global->LDS (already fp16 + swizzled in ws)
    const char* gsrc = wtile0 + (size_t)ktl * ((size_t)D_DIM * BK * 2);
#pragma unroll
    for (int i = 0; i < 4; ++i) glds16(gsrc + i * 1024, wldst + i * 1024);

    // stage x tile: f32 load -> fp16 cvt -> swizzled ds_write_b128
    const float* sp = srow + ktl * BK;
    float4 f0 = *(const float4*)(sp);
    float4 f1 = *(const float4*)(sp + 4);
    float4 f2 = *(const float4*)(sp + 8);
    float4 f3 = *(const float4*)(sp + 12);
    *(half8*)xw0 = cvt8(f0, f1);
    *(half8*)xw1 = cvt8(f2, f3);
    __syncthreads();   // compiler drains vmcnt(0)+lgkmcnt(0) here (glds + ds_write complete)

#pragma unroll
    for (int kk = 0; kk < 2; ++kk) {
      half8 af[4], bf[4];
#pragma unroll
      for (int mf = 0; mf < 4; ++mf) {
        int m = wr * 64 + mf * 16 + lr;     // A frag: row = lane&15, k = (lane>>4)*8+j
        af[mf] = *(const half8*)(xs + m * BK + (((kk * 4 + lg) ^ (m & 7)) * 8));
      }
#pragma unroll
      for (int nf = 0; nf < 4; ++nf) {
        int d = wc * 64 + nf * 16 + lr;     // B frag: col = lane&15, k = (lane>>4)*8+j
        bf[nf] = *(const half8*)(wsh + d * BK + (((kk * 4 + lg) ^ (d & 7)) * 8));
      }
#pragma unroll
      for (int mf = 0; mf < 4; ++mf)
#pragma unroll
        for (int nf = 0; nf < 4; ++nf)
          acc[mf][nf] = __builtin_amdgcn_mfma_f32_16x16x32_f16(af[mf], bf[nf], acc[mf][nf], 0, 0, 0);
    }
    __syncthreads();
  }

  // epilogue: fp16 partials. C frag: col = lane&15, row = (lane>>4)*4 + reg  [m89]
  _Float16* Pb = P + ((size_t)kcid * 8192 + (size_t)mt * BM) * D_DIM;
#pragma unroll
  for (int mf = 0; mf < 4; ++mf)
#pragma unroll
    for (int j = 0; j < 4; ++j) {
      _Float16* prow = Pb + (size_t)(wr * 64 + mf * 16 + lg * 4 + j) * D_DIM + wc * 64;
#pragma unroll
      for (int nf = 0; nf < 4; ++nf)
        prow[nf * 16 + lr] = (_Float16)acc[mf][nf][j];
    }
}

// er = r @ W_rel^T (MFMA, K=512) fused with partial-sum reduce, triple product,
// row-sum over D and sigmoid.
#define CBM 32
__global__ __launch_bounds__(256, 2) void er_combine(
    const float* __restrict__ Rm, const _Float16* __restrict__ Wr,
    const _Float16* __restrict__ P, float* __restrict__ out) {
  __shared__ __align__(16) _Float16 rs[CBM * 64];       // 4 KB
  __shared__ __align__(16) _Float16 wrsh[D_DIM * 64];   // 32 KB
  __shared__ float sc[4][CBM];

  const int r0 = blockIdx.x * CBM;
  const int t = threadIdx.x;
  const int w = t >> 6, l = t & 63;     // wave = d-column strip of 64
  const int lr = l & 15, lg = l >> 4;

  const int sm = t >> 3, sseg = t & 7;
  const float* srow = Rm + (size_t)(r0 + sm) * R_DIM + (size_t)sseg * 8;
  _Float16* rw = rs + sm * 64 + ((sseg ^ (sm & 7)) * 8);

  const char* wtile0 = (const char*)Wr + (size_t)w * 8192 + (size_t)l * 16;
  char* wldst = (char*)wrsh + w * 8192;

  f32x4 acc[2][4] = {};

  for (int kt = 0; kt < R_DIM / 64; ++kt) {   // 8 iterations
    const char* gsrc = wtile0 + (size_t)kt * ((size_t)D_DIM * 64 * 2);
#pragma unroll
    for (int i = 0; i < 8; ++i) glds16(gsrc + i * 1024, wldst + i * 1024);
    const float* sp = srow + kt * 64;
    float4 f0 = *(const float4*)sp;
    float4 f1 = *(const float4*)(sp + 4);
    *(half8*)rw = cvt8(f0, f1);
    __syncthreads();
#pragma unroll
    for (int kk = 0; kk < 2; ++kk) {
      half8 af[2], bf[4];
#pragma unroll
      for (int mf = 0; mf < 2; ++mf) {
        int m = mf * 16 + lr;
        af[mf] = *(const half8*)(rs + m * 64 + (((kk * 4 + lg) ^ (m & 7)) * 8));
      }
#pragma unroll
      for (int nf = 0; nf < 4; ++nf) {
        int d = w * 64 + nf * 16 + lr;
        bf[nf] = *(const half8*)(wrsh + d * 64 + (((kk * 4 + lg) ^ (d & 7)) * 8));
      }
#pragma unroll
      for (int mf = 0; mf < 2; ++mf)
#pragma unroll
        for (int nf = 0; nf < 4; ++nf)
          acc[mf][nf] = __builtin_amdgcn_mfma_f32_16x16x32_f16(af[mf], bf[nf], acc[mf][nf], 0, 0, 0);
    }
    __syncthreads();
  }

  // fuse: ea = sum_s P[s][row][d], eb = sum_s P[s][4096+row][d], v = ea*eb*er
  // then reduce over d (16 lanes per group hold consecutive d; 4 nf per lane)
#pragma unroll
  for (int mf = 0; mf < 2; ++mf)
#pragma unroll
    for (int j = 0; j < 4; ++j) {
      int rowl = mf * 16 + lg * 4 + j;
      size_t grow = (size_t)(r0 + rowl);
      float v = 0.f;
#pragma unroll
      for (int nf = 0; nf < 4; ++nf) {
        int d = w * 64 + nf * 16 + lr;
        float ea = 0.f, eb = 0.f;
#pragma unroll
        for (int s = 0; s < 4; ++s) {
          ea += (float)P[((size_t)s * 8192 + grow) * D_DIM + d];
          eb += (float)P[((size_t)s * 8192 + 4096 + grow) * D_DIM + d];
        }
        v += ea * eb * acc[mf][nf][j];
      }
      v += __shfl_xor(v, 1, 64);
      v += __shfl_xor(v, 2, 64);
      v += __shfl_xor(v, 4, 64);
      v += __shfl_xor(v, 8, 64);
      if (lr == 0) sc[w][rowl] = v;
    }
  __syncthreads();
  if (t < CBM) {
    float tot = sc[0][t] + sc[1][t] + sc[2][t] + sc[3][t];
    out[r0 + t] = 1.0f / (1.0f + expf(-tot));
  }
}

extern "C" void kernel_launch(void* const* d_in, const int* in_sizes, int n_in,
                              void* d_out, int out_size, void* d_ws, size_t ws_size,
                              hipStream_t stream) {
  (void)in_sizes; (void)n_in; (void)out_size; (void)ws_size;
  const float* x    = (const float*)d_in[0];
  const float* y    = (const float*)d_in[1];
  const float* r    = (const float*)d_in[2];
  const float* Went = (const float*)d_in[3];
  const float* Wrel = (const float*)d_in[4];
  float* out = (float*)d_out;

  char* ws = (char*)d_ws;
  _Float16* wentf = (_Float16*)(ws + WENT_OFF);
  _Float16* wrelf = (_Float16*)(ws + WREL_OFF);
  _Float16* P     = (_Float16*)(ws + P_OFF);   // total ws use: 25.4 MB

  convert_w<<<dim3((D_DIM * E_DIM / 8) / 256), dim3(256), 0, stream>>>(Went, wentf, E_DIM);
  convert_w<<<dim3((D_DIM * R_DIM / 8) / 256), dim3(256), 0, stream>>>(Wrel, wrelf, R_DIM);
  main_gemm<<<dim3(64 * SSPLIT), dim3(512), 0, stream>>>(x, y, wentf, P);
  er_combine<<<dim3(N_ROWS / CBM), dim3(256), 0, stream>>>(r, wrelf, P, out);
}